// Round 1
// baseline (227.399 us; speedup 1.0000x reference)
//
#include <hip/hip_runtime.h>
#include <math.h>

#define BSZ  32
#define GSZ  50
#define ATOT 8400
#define NCLS 80
#define CDIM 85
#define TPB  256

#define EPSF 1e-7f
#define BIGF 100000.0f
#define INFF 1000000000.0f
#define IMGF 640.0f
#define DISF 20.0f   // 2.5 * stride(8)

__device__ __forceinline__ float sigm(float z){ return 1.0f/(1.0f+expf(-z)); }

__device__ __forceinline__ const float* chan_ptr(const float* __restrict__ p8,
                                                 const float* __restrict__ p16,
                                                 const float* __restrict__ p32,
                                                 int b, int a, int ch){
  if (a < 6400) return p8  + ((size_t)(b*CDIM + ch))*6400 + a;
  if (a < 8000) return p16 + ((size_t)(b*CDIM + ch))*1600 + (a-6400);
  return p32 + ((size_t)(b*CDIM + ch))*400 + (a-8000);
}

// cost/iou/masks for one (gt, anchor) pair — exact reference semantics
__device__ __forceinline__ void compute_pair(
  float cx, float cy, float gw, float gh,
  float px, float py, float pw, float ph,
  float z, float slog,
  float& cost, float& iou, bool& orm, bool& andm, float& clsc)
{
  float hw = gw*0.5f, hh = gh*0.5f;
  bool cm = (px >= fmaxf(cx-DISF,0.f)) && (px <= fminf(cx+DISF,IMGF)) &&
            (py >= fmaxf(cy-DISF,0.f)) && (py <= fminf(cy+DISF,IMGF));
  bool im = (px >= fmaxf(cx-hw,0.f)) && (px <= fminf(cx+hw,IMGF)) &&
            (py >= fmaxf(cy-hh,0.f)) && (py <= fminf(cy+hh,IMGF));
  orm = cm || im;  andm = cm && im;
  float phw = pw*0.5f, phh = ph*0.5f;
  float wx = fmaxf(fminf(cx+hw, px+phw) - fmaxf(cx-hw, px-phw), 0.f);
  float wy = fmaxf(fminf(cy+hh, py+phh) - fmaxf(cy-hh, py-phh), 0.f);
  float inter = wx*wy;
  float uni   = gw*gh + pw*ph - inter;
  iou = inter / fmaxf(uni, 1e-6f);
  float s = sigm(z);
  s = fminf(fmaxf(s, EPSF), 1.f-EPSF);
  clsc = (logf(1.f-s) - logf(s)) - slog;
  cost = clsc + 3.f*(-logf(iou + 1e-8f)) + (andm ? 0.f : BIGF);
}

// ---- K-zero: clear assignment bits + accumulators (ws is poisoned each call)
__global__ void k_zero(unsigned long long* __restrict__ bits,
                       float* __restrict__ accum, int* __restrict__ ngts){
  int t = blockIdx.x*blockDim.x + threadIdx.x;
  if (t < BSZ*ATOT) bits[t] = 0ull;
  if (t == 0){ accum[0] = 0.f; ngts[0] = 0; }
}

// ---- K-prep: per-gt class index (one-hot argmax) + num_gts
__global__ void k_prep(const float* __restrict__ tgt, int* __restrict__ cidx,
                       int* __restrict__ ngts){
  int t = blockIdx.x*blockDim.x + threadIdx.x;
  if (t >= BSZ*GSZ) return;
  const float* T = tgt + (size_t)t*CDIM;
  int best = 0; float bv = T[5];
  for (int c = 1; c < NCLS; c++){
    float v = T[5+c];
    if (v > bv){ bv = v; best = c; }
  }
  cidx[t] = best;
  if (T[4] == 1.0f) atomicAdd(ngts, 1);
}

// ---- K-decode: per-anchor box, obj sigmoid, sum_c log(1-p_c)
__global__ void k_decode(const float* __restrict__ p8, const float* __restrict__ p16,
                         const float* __restrict__ p32,
                         float* __restrict__ bx, float* __restrict__ by,
                         float* __restrict__ bw, float* __restrict__ bh,
                         float* __restrict__ obj, float* __restrict__ slog){
  int t = blockIdx.x*blockDim.x + threadIdx.x;
  if (t >= BSZ*ATOT) return;
  int b = t / ATOT, a = t % ATOT;
  const float* base; int l, stride, aL;
  if (a < 6400){ base = p8;  l = 80; stride = 8;  aL = a; }
  else if (a < 8000){ base = p16; l = 40; stride = 16; aL = a-6400; }
  else { base = p32; l = 20; stride = 32; aL = a-8000; }
  size_t l2 = (size_t)l*l;
  const float* p = base + (size_t)b*CDIM*l2 + aL;
  int i = aL / l, j = aL % l;
  float x = ((float)j + sigm(p[0]))    * (float)stride;
  float y = ((float)i + sigm(p[1*l2])) * (float)stride;
  float w = expf(p[2*l2]) * (float)stride;
  float h = expf(p[3*l2]) * (float)stride;
  float o = sigm(p[4*l2]);
  float s = 0.f;
  for (int c = 0; c < NCLS; c++){
    float pc = sigm(p[(size_t)(5+c)*l2]);
    pc = fminf(fmaxf(pc, EPSF), 1.f-EPSF);
    s += logf(1.f - pc);
  }
  bx[t]=x; by[t]=y; bw[t]=w; bh[t]=h; obj[t]=o; slog[t]=s;
}

// ---- K-assign: one block per (gt g, image b); dynamic-k top-10 assignment
__global__ void k_assign(const float* __restrict__ p8, const float* __restrict__ p16,
                         const float* __restrict__ p32, const float* __restrict__ tgt,
                         const int* __restrict__ cidx,
                         const float* __restrict__ bx, const float* __restrict__ by,
                         const float* __restrict__ bw, const float* __restrict__ bh,
                         const float* __restrict__ slog,
                         unsigned long long* __restrict__ bits){
  int g = blockIdx.x, b = blockIdx.y;
  const float* T = tgt + ((size_t)b*GSZ + g)*CDIM;
  if (T[4] != 1.0f) return;                 // invalid gt: or_m all false, no keeps
  float cx = T[0], cy = T[1], gw = T[2], gh = T[3];
  int ch = 5 + cidx[b*GSZ + g];
  int t = threadIdx.x;

  const float* BX = bx + (size_t)b*ATOT;
  const float* BY = by + (size_t)b*ATOT;
  const float* BW = bw + (size_t)b*ATOT;
  const float* BH = bh + (size_t)b*ATOT;
  const float* SL = slog + (size_t)b*ATOT;

  // per-thread top-10 (cost ascending w/ index; iou descending, values only)
  float lc[10]; int li[10]; float lio[10];
  #pragma unroll
  for (int k = 0; k < 10; k++){ lc[k] = 1e30f; li[k] = -1; lio[k] = 0.f; }
  int my_and = 0;

  for (int a = t; a < ATOT; a += TPB){
    float z = *chan_ptr(p8, p16, p32, b, a, ch);
    float cost, iou, clsc; bool orm, andm;
    compute_pair(cx, cy, gw, gh, BX[a], BY[a], BW[a], BH[a], z, SL[a],
                 cost, iou, orm, andm, clsc);
    if (!orm) continue;                     // or_m includes &valid; and_m => or_m
    my_and += andm ? 1 : 0;
    if (cost < lc[9]){                      // stable: equal keeps earlier (lower a)
      float v = cost; int vi = a;
      #pragma unroll
      for (int k = 0; k < 10; k++){
        if (v < lc[k]){ float tv = lc[k]; int ti = li[k];
                        lc[k] = v; li[k] = vi; v = tv; vi = ti; }
      }
    }
    if (iou > lio[9]){
      float v = iou;
      #pragma unroll
      for (int k = 0; k < 10; k++){
        if (v > lio[k]){ float tv = lio[k]; lio[k] = v; v = tv; }
      }
    }
  }

  __shared__ float sc[TPB*10]; __shared__ int si[TPB*10]; __shared__ float sio[TPB*10];
  __shared__ int hp[TPB]; __shared__ int hq[TPB];
  __shared__ float rv[TPB]; __shared__ int ri[TPB]; __shared__ int rw[TPB];
  __shared__ int merged_i[10];
  __shared__ float k10s; __shared__ int and_sh;

  #pragma unroll
  for (int k = 0; k < 10; k++){ sc[t*10+k] = lc[k]; si[t*10+k] = li[k]; sio[t*10+k] = lio[k]; }
  hp[t] = 0; hq[t] = 0;
  if (t == 0){ and_sh = 0; k10s = 0.f; }
  __syncthreads();
  atomicAdd(&and_sh, my_and);
  __syncthreads();

  // merge: 10 rounds of tournament-min over 256 sorted heads (cost)
  for (int r = 0; r < 10; r++){
    float v; int idx;
    if (hp[t] < 10){ v = sc[t*10+hp[t]]; idx = si[t*10+hp[t]]; }
    else           { v = 3.4e38f;        idx = -1; }
    rv[t] = v; ri[t] = idx; rw[t] = t;
    __syncthreads();
    for (int s2 = TPB/2; s2 > 0; s2 >>= 1){
      if (t < s2){
        float v2 = rv[t+s2]; int i2 = ri[t+s2];
        bool better = (v2 < rv[t]) ||
                      (v2 == rv[t] && (unsigned)i2 < (unsigned)ri[t]);
        if (better){ rv[t] = v2; ri[t] = i2; rw[t] = rw[t+s2]; }
      }
      __syncthreads();
    }
    if (t == 0){ merged_i[r] = ri[0]; hp[rw[0]]++; }
    __syncthreads();
  }
  // merge: 10 rounds of tournament-max (iou), sum in descending order
  for (int r = 0; r < 10; r++){
    rv[t] = (hq[t] < 10) ? sio[t*10+hq[t]] : -1.f;
    rw[t] = t;
    __syncthreads();
    for (int s2 = TPB/2; s2 > 0; s2 >>= 1){
      if (t < s2){
        if (rv[t+s2] > rv[t]){ rv[t] = rv[t+s2]; rw[t] = rw[t+s2]; }
      }
      __syncthreads();
    }
    if (t == 0){ k10s += fmaxf(rv[0], 0.f); hq[rw[0]]++; }
    __syncthreads();
  }

  if (t == 0){
    int dk = (int)k10s;                       // trunc like astype(int32)
    if (dk < 1) dk = 1;
    int ub = and_sh > 1 ? and_sh : 1;
    if (dk > ub) dk = ub;
    for (int j = 0; j < dk && j < 10; j++){
      int aa = merged_i[j];
      if (aa < 0) break;                      // exhausted or_m members (INF in ref)
      atomicOr(&bits[(size_t)b*ATOT + aa], 1ull << g);
    }
  }
}

// ---- K-loss: overlap resolution + conf/cls/reg losses, block-reduced
__global__ void k_loss(const float* __restrict__ p8, const float* __restrict__ p16,
                       const float* __restrict__ p32, const float* __restrict__ tgt,
                       const int* __restrict__ cidx,
                       const float* __restrict__ bx, const float* __restrict__ by,
                       const float* __restrict__ bw, const float* __restrict__ bh,
                       const float* __restrict__ obj, const float* __restrict__ slog,
                       const unsigned long long* __restrict__ bits,
                       float* __restrict__ accum){
  int b = blockIdx.y;
  int a = blockIdx.x*TPB + threadIdx.x;
  __shared__ float gcx[GSZ], gcy[GSZ], ggw[GSZ], ggh[GSZ], gval[GSZ];
  __shared__ int gci[GSZ];
  for (int k = threadIdx.x; k < GSZ; k += TPB){
    const float* T = tgt + ((size_t)b*GSZ + k)*CDIM;
    gcx[k] = T[0]; gcy[k] = T[1]; ggw[k] = T[2]; ggh[k] = T[3]; gval[k] = T[4];
    gci[k] = cidx[b*GSZ + k];
  }
  __syncthreads();

  float contrib = 0.f;
  if (a < ATOT){
    size_t t = (size_t)b*ATOT + a;
    unsigned long long m = bits[t];
    float px = bx[t], py = by[t], pw = bw[t], ph = bh[t], sl = slog[t];
    if (__builtin_popcountll(m) > 1){
      // argmin over cost_full (INF for invalid rows); first-min-index like jnp.argmin
      float bestc = INFF; int bestg = 0;
      for (int g = 0; g < GSZ; g++){
        float c = INFF;
        if (gval[g] == 1.0f){
          float z = *chan_ptr(p8, p16, p32, b, a, 5+gci[g]);
          float iou, clsc; bool orm, andm;
          compute_pair(gcx[g], gcy[g], ggw[g], ggh[g], px, py, pw, ph, z, sl,
                       c, iou, orm, andm, clsc);
        }
        if (c < bestc){ bestc = c; bestg = g; }
      }
      m = 1ull << bestg;
    }
    bool fg = (m != 0ull);
    float o = fminf(fmaxf(obj[t], EPSF), 1.f-EPSF);
    contrib = fg ? -logf(o) : -logf(1.f - o);     // conf BCE
    while (m){
      int g = __builtin_ctzll(m);
      m &= m - 1;
      float z = *chan_ptr(p8, p16, p32, b, a, 5+gci[g]);
      float c, iou, clsc; bool orm, andm;
      compute_pair(gcx[g], gcy[g], ggw[g], ggh[g], px, py, pw, ph, z, sl,
                   c, iou, orm, andm, clsc);
      contrib += clsc + 5.f*(1.f - iou*iou);      // l_cls + reg_weight*l_reg
    }
  }

  __shared__ float red[TPB];
  red[threadIdx.x] = contrib;
  __syncthreads();
  for (int s = TPB/2; s > 0; s >>= 1){
    if (threadIdx.x < s) red[threadIdx.x] += red[threadIdx.x + s];
    __syncthreads();
  }
  if (threadIdx.x == 0) atomicAdd(accum, red[0]);
}

// ---- K-final
__global__ void k_final(const float* __restrict__ accum, const int* __restrict__ ngts,
                        float* __restrict__ out){
  int n = ngts[0] < 1 ? 1 : ngts[0];
  out[0] = accum[0] / (float)n;
}

extern "C" void kernel_launch(void* const* d_in, const int* in_sizes, int n_in,
                              void* d_out, int out_size, void* d_ws, size_t ws_size,
                              hipStream_t stream) {
  const float* p8  = (const float*)d_in[0];
  const float* p16 = (const float*)d_in[1];
  const float* p32 = (const float*)d_in[2];
  const float* tgt = (const float*)d_in[3];
  float* out = (float*)d_out;

  const size_t BA = (size_t)BSZ*ATOT;
  float* bx   = (float*)d_ws;
  float* by   = bx + BA;
  float* bw   = by + BA;
  float* bh   = bw + BA;
  float* obj  = bh + BA;
  float* slog = obj + BA;
  unsigned long long* bits = (unsigned long long*)(slog + BA);  // 6*BA*4 is 8B-aligned
  int* cidx = (int*)(bits + BA);
  int* ngts = cidx + BSZ*GSZ;
  float* accum = (float*)(ngts + 1);

  dim3 blk(TPB);
  k_zero  <<<dim3((unsigned)((BA + TPB-1)/TPB)), blk, 0, stream>>>(bits, accum, ngts);
  k_prep  <<<dim3((BSZ*GSZ + TPB-1)/TPB), blk, 0, stream>>>(tgt, cidx, ngts);
  k_decode<<<dim3((unsigned)((BA + TPB-1)/TPB)), blk, 0, stream>>>(p8, p16, p32,
                                                   bx, by, bw, bh, obj, slog);
  k_assign<<<dim3(GSZ, BSZ), blk, 0, stream>>>(p8, p16, p32, tgt, cidx,
                                               bx, by, bw, bh, slog, bits);
  k_loss  <<<dim3((ATOT + TPB-1)/TPB, BSZ), blk, 0, stream>>>(p8, p16, p32, tgt, cidx,
                                               bx, by, bw, bh, obj, slog, bits, accum);
  k_final <<<1, 1, 0, stream>>>(accum, ngts, out);
}